// Round 18
// baseline (371.867 us; speedup 1.0000x reference)
//
#include <hip/hip_runtime.h>

typedef short short8 __attribute__((ext_vector_type(8)));
typedef short short4v __attribute__((ext_vector_type(4)));
typedef float floatx16 __attribute__((ext_vector_type(16)));
typedef float floatx4 __attribute__((ext_vector_type(4)));

#define ROWS 81
#define CDIM 256
// LDS layout: XT bf16 [81][256] p-major rows (r=p*9+m), swizzle SWX, stride 512B
//             QT bf16 [96][128] (padded rows), swizzle (r&15)<<4, stride 256B
//             AB: 8 private attn slots, [16][16] bf16 each (512B per wave)
#define XT   0
#define QT   41472
#define AB   66048
#define TOT  70144

#define SWX(r) ((((r) & 15) << 4) ^ (((r) & 8) << 3))

__device__ __forceinline__ unsigned short f2bf(float f) {
    union { float f; unsigned int u; } v; v.f = f;
    return (unsigned short)((v.u + 0x7FFFu + ((v.u >> 16) & 1u)) >> 16);
}

__device__ __forceinline__ unsigned int cvtpk(float lo, float hi) {
    unsigned int r;
    asm("v_cvt_pk_bf16_f32 %0, %1, %2" : "=v"(r) : "v"(lo), "v"(hi));
    return r;
}

__global__ void wconv_kernel(const float* __restrict__ W,
                             unsigned short* __restrict__ Wb, int n) {
    int i = blockIdx.x * 256 + threadIdx.x;
    if (i < n) Wb[i] = f2bf(W[i]);
}

__device__ __forceinline__ void stage_store(char* smem, int k, float4 a0, float4 a1) {
    int gr = k >> 5;
    int c0 = (k & 31) * 8;            // f32 col base
    int hh = gr / 9, ww = gr - hh * 9;
    int p = (hh % 3) * 3 + (ww % 3);
    int m = (hh / 3) * 3 + (ww / 3);
    int r = p * 9 + m;
    uint4 v;
    v.x = cvtpk(a0.x, a0.y);
    v.y = cvtpk(a0.z, a0.w);
    v.z = cvtpk(a1.x, a1.y);
    v.w = cvtpk(a1.z, a1.w);
    *(uint4*)(smem + XT + r * 512 + ((c0 * 2) ^ SWX(r))) = v;
}

__global__ __launch_bounds__(512, 2)
void attn_kernel(const float* __restrict__ x,
                 const unsigned short* __restrict__ Wb,
                 const float* __restrict__ b_fc,
                 const int* __restrict__ block_idx,
                 const int* __restrict__ match_vec,
                 float* __restrict__ out)
{
    __shared__ __align__(16) char smem[TOT];
    const int b     = blockIdx.x;
    const int t     = threadIdx.x;
    const int lane  = t & 63;
    const int wave  = t >> 6;       // 0..7
    const int l15   = lane & 15;
    const int kg    = lane >> 4;    // 0..3
    const int l31   = lane & 31;
    const int khalf = lane >> 5;    // 0..1

    const int cm = match_vec[block_idx[b]];   // uniform (scalar) load

    // ---- proj tiling: wave -> 48 rows x 32 h-cols ----
    const int rh = (wave & 1) * 48;       // row half
    const int hg = (wave >> 1) * 32;      // h group (32 cols)

    // W^T B-fragments: 2 sets of 16 h-cols (L2-hot)
    short8 wfrag[2][8];
#pragma unroll
    for (int s2 = 0; s2 < 2; ++s2) {
        const unsigned short* wr = Wb + (hg + s2 * 16 + l15) * CDIM + kg * 8;
#pragma unroll
        for (int ks = 0; ks < 8; ++ks)
            wfrag[s2][ks] = *(const short8*)(wr + ks * 32);
    }
    float bias2[2];
    bias2[0] = b_fc[hg + l15];
    bias2[1] = b_fc[hg + 16 + l15];

    // ---- stage x -> XT: issue ALL loads first (one HBM latency), then store ----
    {
        const float* xb = x + (size_t)b * (ROWS * CDIM);
        float4 a0[5], a1[5], t0, t1;
#pragma unroll
        for (int j = 0; j < 5; ++j) {
            int k = t + 512 * j;
            a0[j] = *(const float4*)(xb + k * 8);
            a1[j] = *(const float4*)(xb + k * 8 + 4);
        }
        const bool tail = (t < 32);
        if (tail) {
            t0 = *(const float4*)(xb + (2560 + t) * 8);
            t1 = *(const float4*)(xb + (2560 + t) * 8 + 4);
        }
#pragma unroll
        for (int j = 0; j < 5; ++j) stage_store(smem, t + 512 * j, a0[j], a1[j]);
        if (tail) stage_store(smem, 2560 + t, t0, t1);
    }
    __syncthreads();   // B0: XT ready

    // ---- proj: q[96x128] = x @ W^T via 16x16x32: 3 row-tiles x 2 h-sets x 8 k ----
    {
        floatx4 acc[3][2];
#pragma unroll
        for (int ii = 0; ii < 3; ++ii)
#pragma unroll
            for (int s2 = 0; s2 < 2; ++s2)
#pragma unroll
                for (int j = 0; j < 4; ++j) acc[ii][s2][j] = 0.f;
        __builtin_amdgcn_s_setprio(1);
#pragma unroll
        for (int ks = 0; ks < 8; ++ks) {
            int cb = ks * 64 + kg * 16;       // byte offset of k-chunk
#pragma unroll
            for (int tile = 0; tile < 3; ++tile) {
                int r = rh + tile * 16 + l15;
                short8 a = *(const short8*)(smem + XT + r * 512 + (cb ^ SWX(r)));
                acc[tile][0] = __builtin_amdgcn_mfma_f32_16x16x32_bf16(a, wfrag[0][ks], acc[tile][0], 0, 0, 0);
                acc[tile][1] = __builtin_amdgcn_mfma_f32_16x16x32_bf16(a, wfrag[1][ks], acc[tile][1], 0, 0, 0);
            }
        }
        __builtin_amdgcn_s_setprio(0);
#pragma unroll
        for (int tile = 0; tile < 3; ++tile)
#pragma unroll
            for (int s2 = 0; s2 < 2; ++s2) {
                int h2 = (hg + s2 * 16 + l15) * 2;
#pragma unroll
                for (int reg = 0; reg < 4; ++reg) {
                    int r = rh + tile * 16 + kg * 4 + reg;   // 0..95, QT padded
                    *(unsigned short*)(smem + QT + r * 256 + (h2 ^ ((r & 15) << 4))) =
                        f2bf(acc[tile][s2][reg] + bias2[s2]);
                }
            }
    }
    __syncthreads();   // B1: q ready — LAST barrier; waves now fully independent

    // ---- per-wave redundant gram: 4 interleaved chains, 36 MFMA ----
    char* slot = smem + AB + wave * 512;   // private attn tile [16][16] bf16
    {
        floatx4 s0, s1, s2, s3;
#pragma unroll
        for (int ii = 0; ii < 4; ++ii) { s0[ii] = 0.f; s1[ii] = 0.f; s2[ii] = 0.f; s3[ii] = 0.f; }
        const int nc = (l15 < 9) ? l15 : 8;
#pragma unroll
        for (int s = 0; s < 9; ++s) {
#pragma unroll
            for (int ii = 0; ii < 4; ++ii) {
                int ks = ii + s * 4;              // 0..35
                int kk = ks * 32 + kg * 8;
                int p  = kk >> 7;
                int h0 = (kk & 127) * 2;
                int row = p * 9 + nc;
                short8 f = *(const short8*)(smem + QT + row * 256 + (h0 ^ ((row & 15) << 4)));
                floatx4 tmp = __builtin_amdgcn_mfma_f32_16x16x32_bf16(
                    f, f, (ii == 0 ? s0 : ii == 1 ? s1 : ii == 2 ? s2 : s3), 0, 0, 0);
                if (ii == 0) s0 = tmp; else if (ii == 1) s1 = tmp; else if (ii == 2) s2 = tmp; else s3 = tmp;
            }
        }

        // ---- in-register softmax: S[m][n] at (m=kg*4+reg, n=l15); S symmetric ----
        const float scale = 0.029462782549439483f;   // (128*9)^-0.5
        float sv[4];
#pragma unroll
        for (int reg = 0; reg < 4; ++reg) {
            int m = kg * 4 + reg;
            float v = (s0[reg] + s1[reg] + s2[reg] + s3[reg]) * scale;
            if (m == l15 && cm != 1) v -= 100.f;
            sv[reg] = (m <= 8) ? v : -1e30f;      // mask pad rows
        }
        float mx = fmaxf(fmaxf(sv[0], sv[1]), fmaxf(sv[2], sv[3]));
        mx = fmaxf(mx, __shfl_xor(mx, 16));
        mx = fmaxf(mx, __shfl_xor(mx, 32));       // column max over m
        float e0 = __expf(sv[0] - mx), e1 = __expf(sv[1] - mx);
        float e2 = __expf(sv[2] - mx), e3 = __expf(sv[3] - mx);
        float sum = e0 + e1 + e2 + e3;
        sum += __shfl_xor(sum, 16);
        sum += __shfl_xor(sum, 32);               // column sum over m
        float inv = 1.f / sum;
        short4v aw;
        aw[0] = (short)f2bf(e0 * inv);            // pad m>8 -> exp(-huge)=0 -> bf16 0
        aw[1] = (short)f2bf(e1 * inv);
        aw[2] = (short)f2bf(e2 * inv);
        aw[3] = (short)f2bf(e3 * inv);
        *(short4v*)(slot + l15 * 32 + kg * 8) = aw;   // attn[n=l15][m=kg*4..+3]
        // same-wave LDS write->read below; compiler inserts lgkmcnt wait
    }

    // ---- epilogue: out^T = v^T @ attn^T via 32x32x16; private bf slot ----
    // tile = wave + 8*pp  =>  p = pp (compile-time), c = wave*32 + l31 (invariant)
    {
        const int n  = l31;
        const int nm = (n < 9) ? n : 0;
        short8 bf = *(const short8*)(slot + nm * 32 + khalf * 16);
        floatx16 zero16;
#pragma unroll
        for (int ii = 0; ii < 16; ++ii) zero16[ii] = 0.f;
        float* ob = out + (size_t)b * (ROWS * CDIM);
        int nbase = 0;
        if (n < 9) nbase = ((n / 3) * 3) * 9 + (n % 3) * 3;   // output row base
        const int c2 = (wave * 32 + l31) * 2;                 // byte col in XT row
#pragma unroll
        for (int pp = 0; pp < 9; ++pp) {
            short8 af;
#pragma unroll
            for (int j = 0; j < 8; ++j) {
                int mm = khalf ? 8 : j;          // khalf=1: attn cols 9..15 are 0
                int row = pp * 9 + mm;           // compile-time given khalf
                af[j] = *(const short*)(smem + XT + row * 512 + (c2 ^ SWX(row)));
            }
            floatx16 dacc = __builtin_amdgcn_mfma_f32_32x32x16_bf16(af, bf, zero16, 0, 0, 0);
            if (n < 9) {
                const int gr = nbase + (pp / 3) * 9 + (pp % 3);
#pragma unroll
                for (int q2 = 0; q2 < 4; ++q2) {
                    int c0 = wave * 32 + q2 * 8 + khalf * 4;
                    *(float4*)(ob + gr * CDIM + c0) =
                        make_float4(dacc[q2 * 4 + 0], dacc[q2 * 4 + 1],
                                    dacc[q2 * 4 + 2], dacc[q2 * 4 + 3]);
                }
            }
        }
    }
}

extern "C" void kernel_launch(void* const* d_in, const int* in_sizes, int n_in,
                              void* d_out, int out_size, void* d_ws, size_t ws_size,
                              hipStream_t stream) {
    const float* x    = (const float*)d_in[0];
    const float* W    = (const float*)d_in[1];
    const float* bfc  = (const float*)d_in[2];
    const int*   bidx = (const int*)d_in[3];
    const int*   mvec = (const int*)d_in[4];
    float* outp = (float*)d_out;
    unsigned short* Wb = (unsigned short*)d_ws;

    int nW = in_sizes[1];                       // 128*256
    wconv_kernel<<<(nW + 255) / 256, 256, 0, stream>>>(W, Wb, nW);

    int B = in_sizes[0] / (ROWS * CDIM);        // 8192
    attn_kernel<<<B, 512, 0, stream>>>(x, Wb, bfc, bidx, mvec, outp);
}